// Round 9
// baseline (26.531 us; speedup 1.0000x reference)
//
#include <hip/hip_runtime.h>

#define IMW 512
#define IMH 512

typedef float f32x4 __attribute__((ext_vector_type(4)));

__device__ __forceinline__ void s2(float& a, float& b) {
    float t = fminf(a, b);
    b = fmaxf(a, b);
    a = t;
}
__device__ __forceinline__ float max3f(float a, float b, float c) {
    return fmaxf(fmaxf(a, b), c);   // v_max3_f32
}
__device__ __forceinline__ float min3f(float a, float b, float c) {
    return fminf(fminf(a, b), c);   // v_min3_f32
}
__device__ __forceinline__ float med3f(float a, float b, float c) {
    return __builtin_amdgcn_fmed3f(a, b, c);  // v_med3_f32
}

// R8 = R4 winner (4-row tile, XCD swizzle, NT stores) widened to 8 cols:
// per thread 4 output rows x 8 cols; input rows y-1..y+4, cols xo-1..xo+8.
// 12 vec loads + 12 predicated edge scalars + 8 NT stores per 32 px
// (1.0 VMEM inst/px vs 1.375 for 4x4). Shared column pair-sorts (B,C),(D,E)
// feed the 4 vertical triples. Column tags: z (left halo), 0..7, r (right).
__global__ void __launch_bounds__(256)
median3_4x8(const float* __restrict__ in, float* __restrict__ out) {
    // 1536 blocks = 8 XCDs x 192 contiguous -> each XCD owns 6 full planes,
    // vertical halo reuse between adjacent row-quads stays in one L2 (R7
    // showed removing this costs ~1.8 us).
    const int bid = (int)blockIdx.x;
    const int wg  = (bid & 7) * 192 + (bid >> 3);

    const int g     = wg * 256 + (int)threadIdx.x;
    const int xt    = g & 63;            // 8-px slot in row (64 per row)
    const int quad  = (g >> 6) & 127;    // row-quad 0..127
    const int plane = g >> 13;           // 0..47
    const int y     = quad << 2;         // 0,4,...,508
    const int xo    = xt << 3;           // 0..504
    const int base  = (plane << 18) + (y << 9) + xo;

    const bool has_left  = (xo > 0);
    const bool has_right = (xo < IMW - 8);
    const bool has_top   = (y > 0);          // wave-uniform
    const bool has_bot   = (y < IMH - 4);    // wave-uniform

    // rows A=y-1 .. F=y+4; cols z,0..7,r = xo-1, xo..xo+7, xo+8
    float Az,A0,A1,A2,A3,A4,A5,A6,A7,Ar, Bz,B0,B1,B2,B3,B4,B5,B6,B7,Br,
          Cz,C0,C1,C2,C3,C4,C5,C6,C7,Cr, Dz,D0,D1,D2,D3,D4,D5,D6,D7,Dr,
          Ez,E0,E1,E2,E3,E4,E5,E6,E7,Er, Fz,F0,F1,F2,F3,F4,F5,F6,F7,Fr;

#define LOADR(Pz,P0,P1,P2,P3,P4,P5,P6,P7,Pr, RP)            \
    {                                                       \
        const float* rp_ = (RP);                            \
        f32x4 v0 = *reinterpret_cast<const f32x4*>(rp_);    \
        f32x4 v1 = *reinterpret_cast<const f32x4*>(rp_+4);  \
        P0=v0.x; P1=v0.y; P2=v0.z; P3=v0.w;                 \
        P4=v1.x; P5=v1.y; P6=v1.z; P7=v1.w;                 \
        Pz = has_left  ? rp_[-1] : 0.0f;                    \
        Pr = has_right ? rp_[8]  : 0.0f;                    \
    }

    LOADR(Bz,B0,B1,B2,B3,B4,B5,B6,B7,Br, in + base)
    LOADR(Cz,C0,C1,C2,C3,C4,C5,C6,C7,Cr, in + base + IMW)
    LOADR(Dz,D0,D1,D2,D3,D4,D5,D6,D7,Dr, in + base + 2 * IMW)
    LOADR(Ez,E0,E1,E2,E3,E4,E5,E6,E7,Er, in + base + 3 * IMW)
    if (has_top) {
        LOADR(Az,A0,A1,A2,A3,A4,A5,A6,A7,Ar, in + base - IMW)
    } else {
        Az=A0=A1=A2=A3=A4=A5=A6=A7=Ar=0.0f;
    }
    if (has_bot) {
        LOADR(Fz,F0,F1,F2,F3,F4,F5,F6,F7,Fr, in + base + 4 * IMW)
    } else {
        Fz=F0=F1=F2=F3=F4=F5=F6=F7=Fr=0.0f;
    }
#undef LOADR

#define FORCOLS(X) X(z) X(0) X(1) X(2) X(3) X(4) X(5) X(6) X(7) X(r)

    // Shared pair-sorts per column: (B,C)->L1/H1, (D,E)->L2/H2.
    float L1z,L10,L11,L12,L13,L14,L15,L16,L17,L1r,
          H1z,H10,H11,H12,H13,H14,H15,H16,H17,H1r,
          L2z,L20,L21,L22,L23,L24,L25,L26,L27,L2r,
          H2z,H20,H21,H22,H23,H24,H25,H26,H27,H2r;
#define PAIRS(c) \
    L1##c = fminf(B##c, C##c); H1##c = fmaxf(B##c, C##c); \
    L2##c = fminf(D##c, E##c); H2##c = fmaxf(D##c, E##c);
    FORCOLS(PAIRS)
#undef PAIRS

#define MERGESTORE(PTR) { f32x4 o0_, o1_;                                      \
    o0_.x = med3f(max3f(nz,n0,n1), med3f(mz,m0,m1), min3f(xz,x0,x1));          \
    o0_.y = med3f(max3f(n0,n1,n2), med3f(m0,m1,m2), min3f(x0,x1,x2));          \
    o0_.z = med3f(max3f(n1,n2,n3), med3f(m1,m2,m3), min3f(x1,x2,x3));          \
    o0_.w = med3f(max3f(n2,n3,n4), med3f(m2,m3,m4), min3f(x2,x3,x4));          \
    o1_.x = med3f(max3f(n3,n4,n5), med3f(m3,m4,m5), min3f(x3,x4,x5));          \
    o1_.y = med3f(max3f(n4,n5,n6), med3f(m4,m5,m6), min3f(x4,x5,x6));          \
    o1_.z = med3f(max3f(n5,n6,n7), med3f(m5,m6,m7), min3f(x5,x6,x7));          \
    o1_.w = med3f(max3f(n6,n7,nr), med3f(m6,m7,mr), min3f(x6,x7,xr));          \
    __builtin_nontemporal_store(o0_, reinterpret_cast<f32x4*>(PTR));           \
    __builtin_nontemporal_store(o1_, reinterpret_cast<f32x4*>((PTR) + 4)); }

    {   // row 0: triple (A,B,C) = insert A below sorted pair (L1,H1)
#define I(c) float n##c=A##c, m##c=L1##c, x##c=H1##c; s2(n##c,m##c); s2(m##c,x##c);
        FORCOLS(I)
#undef I
        MERGESTORE(out + base)
    }
    {   // row 1: triple (B,C,D) = insert D above sorted pair (L1,H1)
#define I(c) float n##c=L1##c, m##c=H1##c, x##c=D##c; s2(m##c,x##c); s2(n##c,m##c);
        FORCOLS(I)
#undef I
        MERGESTORE(out + base + IMW)
    }
    {   // row 2: triple (C,D,E) = insert C below sorted pair (L2,H2)
#define I(c) float n##c=C##c, m##c=L2##c, x##c=H2##c; s2(n##c,m##c); s2(m##c,x##c);
        FORCOLS(I)
#undef I
        MERGESTORE(out + base + 2 * IMW)
    }
    {   // row 3: triple (D,E,F) = insert F above sorted pair (L2,H2)
#define I(c) float n##c=L2##c, m##c=H2##c, x##c=F##c; s2(m##c,x##c); s2(n##c,m##c);
        FORCOLS(I)
#undef I
        MERGESTORE(out + base + 3 * IMW)
    }
#undef MERGESTORE
#undef FORCOLS
}

extern "C" void kernel_launch(void* const* d_in, const int* in_sizes, int n_in,
                              void* d_out, int out_size, void* d_ws, size_t ws_size,
                              hipStream_t stream) {
    const float* x = (const float*)d_in[0];
    float* out = (float*)d_out;
    // 12,582,912 px / 32 px-per-thread / 256 threads = 1536 blocks
    const int blocks = in_sizes[0] / 32 / 256;
    median3_4x8<<<blocks, 256, 0, stream>>>(x, out);
}

// Round 10
// 21.376 us; speedup vs baseline: 1.2412x; 1.2412x over previous
//
#include <hip/hip_runtime.h>

#define IMW 512
#define IMH 512

typedef float f32x4 __attribute__((ext_vector_type(4)));

__device__ __forceinline__ void s2(float& a, float& b) {
    float t = fminf(a, b);
    b = fmaxf(a, b);
    a = t;
}
__device__ __forceinline__ float max3f(float a, float b, float c) {
    return fmaxf(fmaxf(a, b), c);   // v_max3_f32
}
__device__ __forceinline__ float min3f(float a, float b, float c) {
    return fminf(fminf(a, b), c);   // v_min3_f32
}
__device__ __forceinline__ float med3f(float a, float b, float c) {
    return __builtin_amdgcn_fmed3f(a, b, c);  // v_med3_f32
}

// R9 = R4 verbatim (best measured: 21.26 us).
// 4 output rows x 4 cols per thread; input rows y-1..y+4, cols xpix-1..xpix+4.
// XCD swizzle (R7 A/B: removing costs +1.8us), NT stores (R5 A/B: plain +0.8us),
// 4x4 tile (2x4: +1.4us, 4x8: +5.3us, row-wave shfl: +11us).
__global__ void __launch_bounds__(256)
median3_4x4(const float* __restrict__ in, float* __restrict__ out) {
    // 3072 blocks = 8 XCDs x 384 contiguous -> each XCD owns 6 full planes.
    const int bid = (int)blockIdx.x;
    const int wg  = (bid & 7) * 384 + (bid >> 3);

    const int g     = wg * 256 + (int)threadIdx.x;
    const int xt    = g & 127;           // float4 slot in row
    const int quad  = (g >> 7) & 127;    // row-quad 0..127
    const int plane = g >> 14;           // 0..47
    const int y     = quad << 2;         // 0,4,...,508
    const int xpix  = xt << 2;
    const int base  = (plane << 18) + (y << 9) + xpix;

    const bool has_left  = (xpix > 0);
    const bool has_right = (xpix < IMW - 4);
    const bool has_top   = (y > 0);          // wave-uniform
    const bool has_bot   = (y < IMH - 4);    // wave-uniform

    // rows: A=y-1, B=y, C=y+1, D=y+2, E=y+3, F=y+4; cols 0..5 = xpix-1..xpix+4
    float A0,A1,A2,A3,A4,A5, B0,B1,B2,B3,B4,B5, C0,C1,C2,C3,C4,C5,
          D0,D1,D2,D3,D4,D5, E0,E1,E2,E3,E4,E5, F0,F1,F2,F3,F4,F5;

#define LOADR(P0,P1,P2,P3,P4,P5, RP)                        \
    {                                                       \
        const float* rp_ = (RP);                            \
        f32x4 v = *reinterpret_cast<const f32x4*>(rp_);     \
        P1 = v.x; P2 = v.y; P3 = v.z; P4 = v.w;             \
        P0 = has_left  ? rp_[-1] : 0.0f;                    \
        P5 = has_right ? rp_[4]  : 0.0f;                    \
    }

    LOADR(B0,B1,B2,B3,B4,B5, in + base)
    LOADR(C0,C1,C2,C3,C4,C5, in + base + IMW)
    LOADR(D0,D1,D2,D3,D4,D5, in + base + 2 * IMW)
    LOADR(E0,E1,E2,E3,E4,E5, in + base + 3 * IMW)
    if (has_top) {
        LOADR(A0,A1,A2,A3,A4,A5, in + base - IMW)
    } else {
        A0=A1=A2=A3=A4=A5=0.0f;
    }
    if (has_bot) {
        LOADR(F0,F1,F2,F3,F4,F5, in + base + 4 * IMW)
    } else {
        F0=F1=F2=F3=F4=F5=0.0f;
    }
#undef LOADR

    // Shared pair-sorts per column: (B,C) -> L1/H1, (D,E) -> L2/H2.
    float L10,L11,L12,L13,L14,L15, H10,H11,H12,H13,H14,H15,
          L20,L21,L22,L23,L24,L25, H20,H21,H22,H23,H24,H25;
#define PAIRS(c) \
    L1##c = fminf(B##c, C##c); H1##c = fmaxf(B##c, C##c); \
    L2##c = fminf(D##c, E##c); H2##c = fmaxf(D##c, E##c);
    PAIRS(0) PAIRS(1) PAIRS(2) PAIRS(3) PAIRS(4) PAIRS(5)
#undef PAIRS

    // Insert X below a sorted pair (L,H): sort3 -> (N,M,Xo)
#define INS_BOT(N,M,X, A_,L_,H_) \
    float N = (A_), M = (L_), X = (H_); s2(N, M); s2(M, X);
    // Insert X above a sorted pair (L,H): sort3 -> (N,M,Xo)
#define INS_TOP(N,M,X, L_,H_,F_) \
    float N = (L_), M = (H_), X = (F_); s2(M, X); s2(N, M);

#define MERGE(OUT, N0,M0,X0, N1,M1,X1, N2,M2,X2, N3,M3,X3, N4,M4,X4, N5,M5,X5) \
    OUT.x = med3f(max3f(N0,N1,N2), med3f(M0,M1,M2), min3f(X0,X1,X2)); \
    OUT.y = med3f(max3f(N1,N2,N3), med3f(M1,M2,M3), min3f(X1,X2,X3)); \
    OUT.z = med3f(max3f(N2,N3,N4), med3f(M2,M3,M4), min3f(X2,X3,X4)); \
    OUT.w = med3f(max3f(N3,N4,N5), med3f(M3,M4,M5), min3f(X3,X4,X5));

    f32x4 o;
    {   // row 0: triple (A,B,C) = insert A into (L1,H1)
        INS_BOT(n0,m0,x0, A0,L10,H10) INS_BOT(n1,m1,x1, A1,L11,H11)
        INS_BOT(n2,m2,x2, A2,L12,H12) INS_BOT(n3,m3,x3, A3,L13,H13)
        INS_BOT(n4,m4,x4, A4,L14,H14) INS_BOT(n5,m5,x5, A5,L15,H15)
        MERGE(o, n0,m0,x0, n1,m1,x1, n2,m2,x2, n3,m3,x3, n4,m4,x4, n5,m5,x5)
        __builtin_nontemporal_store(o, reinterpret_cast<f32x4*>(out + base));
    }
    {   // row 1: triple (B,C,D) = insert D into (L1,H1)
        INS_TOP(n0,m0,x0, L10,H10,D0) INS_TOP(n1,m1,x1, L11,H11,D1)
        INS_TOP(n2,m2,x2, L12,H12,D2) INS_TOP(n3,m3,x3, L13,H13,D3)
        INS_TOP(n4,m4,x4, L14,H14,D4) INS_TOP(n5,m5,x5, L15,H15,D5)
        MERGE(o, n0,m0,x0, n1,m1,x1, n2,m2,x2, n3,m3,x3, n4,m4,x4, n5,m5,x5)
        __builtin_nontemporal_store(o, reinterpret_cast<f32x4*>(out + base + IMW));
    }
    {   // row 2: triple (C,D,E) = insert C into (L2,H2)
        INS_BOT(n0,m0,x0, C0,L20,H20) INS_BOT(n1,m1,x1, C1,L21,H21)
        INS_BOT(n2,m2,x2, C2,L22,H22) INS_BOT(n3,m3,x3, C3,L23,H23)
        INS_BOT(n4,m4,x4, C4,L24,H24) INS_BOT(n5,m5,x5, C5,L25,H25)
        MERGE(o, n0,m0,x0, n1,m1,x1, n2,m2,x2, n3,m3,x3, n4,m4,x4, n5,m5,x5)
        __builtin_nontemporal_store(o, reinterpret_cast<f32x4*>(out + base + 2 * IMW));
    }
    {   // row 3: triple (D,E,F) = insert F into (L2,H2)
        INS_TOP(n0,m0,x0, L20,H20,F0) INS_TOP(n1,m1,x1, L21,H21,F1)
        INS_TOP(n2,m2,x2, L22,H22,F2) INS_TOP(n3,m3,x3, L23,H23,F3)
        INS_TOP(n4,m4,x4, L24,H24,F4) INS_TOP(n5,m5,x5, L25,H25,F5)
        MERGE(o, n0,m0,x0, n1,m1,x1, n2,m2,x2, n3,m3,x3, n4,m4,x4, n5,m5,x5)
        __builtin_nontemporal_store(o, reinterpret_cast<f32x4*>(out + base + 3 * IMW));
    }
#undef INS_BOT
#undef INS_TOP
#undef MERGE
}

extern "C" void kernel_launch(void* const* d_in, const int* in_sizes, int n_in,
                              void* d_out, int out_size, void* d_ws, size_t ws_size,
                              hipStream_t stream) {
    const float* x = (const float*)d_in[0];
    float* out = (float*)d_out;
    // 12,582,912 px / 16 px-per-thread / 256 = 3072 blocks
    const int blocks = in_sizes[0] / 16 / 256;
    median3_4x4<<<blocks, 256, 0, stream>>>(x, out);
}